// Round 11
// baseline (173.936 us; speedup 1.0000x reference)
//
#include <hip/hip_runtime.h>

#define BB 4
#define QQ 256
#define VV 2048
#define HH 512
#define UU 128

// tanh arg scale folded into projections: C2E = 2*log2(e); exp(x)=exp2(x*LOG2E)
#define C2E   2.8853900817779268f
#define LOG2E 1.4426950408889634f

__device__ __forceinline__ void fma4(float4& a, float s, const float4& w) {
    a.x = fmaf(s, w.x, a.x);
    a.y = fmaf(s, w.y, a.y);
    a.z = fmaf(s, w.z, a.z);
    a.w = fmaf(s, w.w, a.w);
}
__device__ __forceinline__ float2 rcp2(float2 x) {
    return make_float2(__builtin_amdgcn_rcpf(x.x), __builtin_amdgcn_rcpf(x.y));
}
__device__ __forceinline__ float2 mul2(float2 a, float2 b) { return make_float2(a.x*b.x, a.y*b.y); }
__device__ __forceinline__ float2 muls(float2 a, float s)  { return make_float2(a.x*s, a.y*s); }
__device__ __forceinline__ float2 fma2(float2 a, float2 b, float2 c) {
    return make_float2(fmaf(a.x, b.x, c.x), fmaf(a.y, b.y, c.y));
}
__device__ __forceinline__ float2 fmas(float2 a, float s, float2 c) {
    return make_float2(fmaf(a.x, s, c.x), fmaf(a.y, s, c.y));
}

// ---------------------------------------------------------------------------
// Projection GEMM -> EXPONENTIATED, INTERLEAVED transposed output:
//   E[(g,r,j)] = exp2( C2E * sum_h A[r][h]*W[h][4g+j] ),  at (g*ROWS+r)*4+j.
// 32 rows x 128 u per block, 4 rows/thread. grid = 256 (values) + 32 (q).
// Ls epilogue aliases As+Ws. Block 0 zeroes denom.
// ---------------------------------------------------------------------------
__global__ __launch_bounds__(256) void proj_kernel(const float* __restrict__ queries,
                                                   const float* __restrict__ values,
                                                   const float* __restrict__ w1,
                                                   const float* __restrict__ w2,
                                                   float* __restrict__ pqI,
                                                   float* __restrict__ pvI,
                                                   float* __restrict__ denom) {
    __shared__ float smem[32 * 36 + 32 * 128];   // As[32][36] | Ws[32*128]; Ls aliases
    float (*As)[36] = (float(*)[36])smem;        // [k][row]
    float* Ws = smem + 32 * 36;                  // [k][u]
    float (*Ls)[36] = (float(*)[36])smem;        // [u][row], epilogue (after barrier)

    const int bid = blockIdx.x;
    const int tid = threadIdx.x;
    if (bid == 0) *(float4*)&denom[tid * 4] = make_float4(0.f, 0.f, 0.f, 0.f);

    const bool isv = (bid < 256);
    const float* A; const float* W; int b, r0, ROWS; float* Ob;
    if (isv) {                             // values: 8192 rows, 64 blocks/batch
        b = bid >> 6; r0 = (bid & 63) * 32;
        A = values + ((size_t)(b * VV + r0)) * HH;  W = w2;
        Ob = pvI + (size_t)b * UU * VV;  ROWS = VV;
    } else {                               // queries: 1024 rows, 8 blocks/batch
        const int q = bid - 256;
        b = q >> 3; r0 = (q & 7) * 32;
        A = queries + ((size_t)(b * QQ + r0)) * HH; W = w1;
        Ob = pqI + (size_t)b * UU * QQ;  ROWS = QQ;
    }

    const int tx = tid & 31;         // u-group: u = tx*4 .. tx*4+3
    const int ty = tid >> 5;         // row-quad: rows 4ty .. 4ty+3
    float4 acc[4];
#pragma unroll
    for (int j = 0; j < 4; j++) acc[j] = make_float4(0.f, 0.f, 0.f, 0.f);

    for (int k0 = 0; k0 < HH; k0 += 32) {
        {   // A tile: 32 rows x 32 k, transposed store
            const int r = tid >> 3, kk4 = (tid & 7) * 4;
            const float4 a = *(const float4*)&A[(size_t)r * HH + k0 + kk4];
            As[kk4 + 0][r] = a.x; As[kk4 + 1][r] = a.y;
            As[kk4 + 2][r] = a.z; As[kk4 + 3][r] = a.w;
        }
#pragma unroll
        for (int t = 0; t < 4; t++) {  // W tile: 32 k x 128 u
            const int f = tid + t * 256;
            const int kk = f >> 5, u4 = (f & 31) * 4;
            *(float4*)&Ws[kk * 128 + u4] = *(const float4*)&W[(size_t)(k0 + kk) * UU + u4];
        }
        __syncthreads();
#pragma unroll
        for (int kk = 0; kk < 32; kk++) {
            const float4 a = *(const float4*)&As[kk][ty * 4];       // 4 rows
            const float4 w = *(const float4*)&Ws[kk * 128 + tx * 4];
            fma4(acc[0], a.x, w);
            fma4(acc[1], a.y, w);
            fma4(acc[2], a.z, w);
            fma4(acc[3], a.w, w);
        }
        __syncthreads();
    }
#pragma unroll
    for (int j = 0; j < 4; j++) {
        const float aa[4] = {acc[j].x, acc[j].y, acc[j].z, acc[j].w};
#pragma unroll
        for (int i = 0; i < 4; i++)
            Ls[tx * 4 + i][ty * 4 + j] = __builtin_amdgcn_exp2f(aa[i] * C2E);
    }
    __syncthreads();
#pragma unroll
    for (int t = 0; t < 4; t++) {    // 1024 float4 chunks: (g = idx>>5, r = idx&31)
        const int idx = tid + t * 256;
        const int g = idx >> 5, r = idx & 31;
        float4 o;
        o.x = Ls[4 * g + 0][r]; o.y = Ls[4 * g + 1][r];
        o.z = Ls[4 * g + 2][r]; o.w = Ls[4 * g + 3][r];
        *(float4*)&Ob[((size_t)g * ROWS + r0 + r) * 4] = o;
    }
}

// ---------------------------------------------------------------------------
// Fused scores+softmax-numerator+partial-out.
// R11 geometry: 256 threads (4 waves), vtile=128, qtile=16 ->
// grid = 4b * 16qb * 16vs = 1024 = 4 blocks/CU (R10's grid 512 capped
// occupancy at 2 blocks/CU — the grid, not LDS, was the cap).
// Phase A: exp-product grouped-rcp; u-split across thread halves; the
//   u-half combine REUSES att (no cbuf). LDS total 8.3 KB.
// Phase B: qh-only split (each half covers all 128 v; values dup x2 same as
//   R10 per-CU); no LDS reduce, no barrier — direct slab stores.
// vs in low bid bits: each XCD sees ~2 v-slices -> values L2-resident. Keep.
// ---------------------------------------------------------------------------
__global__ __launch_bounds__(256, 4) void fused_kernel(const float* __restrict__ pqI,
                                                       const float* __restrict__ pvI,
                                                       const float* __restrict__ vvec,
                                                       const float* __restrict__ values,
                                                       float* __restrict__ slab,
                                                       float* __restrict__ denom) {
    __shared__ float att[128][16];    // [v][q] 8 KB; also phase-A combine buf
    __shared__ float wred[2][16];
    const int tid = threadIdx.x;
    const int bid = blockIdx.x;
    const int vs = bid & 15, qb = (bid >> 4) & 15, b = bid >> 8;
    const int qbase = qb * 16, vbase = vs * 128;

    // ---- Phase A ----
    const int vloc = tid & 127, uh = tid >> 7;      // uh wave-uniform
    const int v = vbase + vloc;

    float vsum = 0.0f;
#pragma unroll
    for (int u4 = 0; u4 < UU; u4 += 4) {
        const float4 t = *(const float4*)&vvec[u4];
        vsum += t.x + t.y + t.z + t.w;
    }

    const float* pv4 = pvI + (size_t)b * UU * VV + (size_t)v * 4;      // Ev
    const float* pq4 = pqI + (size_t)b * UU * QQ + (size_t)qbase * 4;  // Eq blocks

    float2 acc[8];
#pragma unroll
    for (int p = 0; p < 8; p++) acc[p] = make_float2(0.f, 0.f);

    const int G0 = uh * 16;
    float4 ev = *(const float4*)&pv4[(size_t)G0 * VV * 4];   // prefetch g=0

    for (int g = 0; g < 16; g++) {
        const int G = G0 + g;
        const float* eqp = &pq4[(size_t)G * QQ * 4];  // 16q x 4u, contiguous, uniform
        float4 evn;
        if (g < 15) evn = *(const float4*)&pv4[(size_t)(G + 1) * VV * 4];
        const float4 wq = *(const float4*)&vvec[G * 4];
        const float w0 = 2.f * wq.x, w1 = 2.f * wq.y;
        const float w2 = 2.f * wq.z, w3 = 2.f * wq.w;
#pragma unroll
        for (int p = 0; p < 8; p++) {
            const float4 e0 = *(const float4*)&eqp[(2 * p) * 4];      // q=2p
            const float4 e1 = *(const float4*)&eqp[(2 * p + 1) * 4];  // q=2p+1
            const float2 a1 = make_float2(fmaf(e0.x, ev.x, 1.f), fmaf(e1.x, ev.x, 1.f));
            const float2 b1 = make_float2(fmaf(e0.y, ev.y, 1.f), fmaf(e1.y, ev.y, 1.f));
            const float2 c1 = make_float2(fmaf(e0.z, ev.z, 1.f), fmaf(e1.z, ev.z, 1.f));
            const float2 d1 = make_float2(fmaf(e0.w, ev.w, 1.f), fmaf(e1.w, ev.w, 1.f));
            const float2 pab = mul2(a1, b1), pcd = mul2(c1, d1);
            const float2 nab = fmas(a1, w1, muls(b1, w0));   // w0*b1 + w1*a1
            const float2 ncd = fmas(c1, w3, muls(d1, w2));
            const float2 num = fma2(nab, pcd, mul2(ncd, pab));
            const float2 den = mul2(pab, pcd);
            acc[p] = fma2(num, rcp2(den), acc[p]);
        }
        ev = evn;
    }

    // u-half combine via att reuse: uh=1 dumps raw partials; uh=0 finishes.
    if (uh == 1) {
#pragma unroll
        for (int p = 0; p < 8; p++)
            *(float2*)&att[vloc][2 * p] = acc[p];
    }
    __syncthreads();
    if (uh == 0) {
#pragma unroll
        for (int p = 0; p < 8; p++) {
            const float2 hi = *(const float2*)&att[vloc][2 * p];
            float2 e;
            e.x = __builtin_amdgcn_exp2f((vsum - (acc[p].x + hi.x)) * LOG2E);
            e.y = __builtin_amdgcn_exp2f((vsum - (acc[p].y + hi.y)) * LOG2E);
            *(float2*)&att[vloc][2 * p] = e;
            acc[p] = e;
        }
        // per-wave denom partials over this wave's 64 v
#pragma unroll
        for (int off = 1; off < 64; off <<= 1) {
#pragma unroll
            for (int p = 0; p < 8; p++) {
                acc[p].x += __shfl_xor(acc[p].x, off, 64);
                acc[p].y += __shfl_xor(acc[p].y, off, 64);
            }
        }
        if ((tid & 63) == 0) {
            const int w = tid >> 6;   // 0..1
#pragma unroll
            for (int p = 0; p < 8; p++) {
                wred[w][2 * p + 0] = acc[p].x;
                wred[w][2 * p + 1] = acc[p].y;
            }
        }
    }
    __syncthreads();
    if (tid < 16)
        atomicAdd(&denom[b * QQ + qbase + tid], wred[0][tid] + wred[1][tid]);

    // ---- Phase B: qh split across thread halves; all 128 v each ----
    const int hg = tid & 127, qh = tid >> 7;        // qh wave-uniform
    const int h0 = hg * 4;
    const float* vp = values + ((size_t)(b * VV + vbase)) * HH + h0;

    float4 oacc[8];
#pragma unroll
    for (int j = 0; j < 8; j++) oacc[j] = make_float4(0.f, 0.f, 0.f, 0.f);

#pragma unroll 2
    for (int vv = 0; vv < 128; vv++) {
        const float4 w = *(const float4*)&vp[(size_t)vv * HH];
        const float4 a0 = *(const float4*)&att[vv][qh * 8 + 0];   // broadcast b128
        const float4 a1 = *(const float4*)&att[vv][qh * 8 + 4];
        fma4(oacc[0], a0.x, w); fma4(oacc[1], a0.y, w);
        fma4(oacc[2], a0.z, w); fma4(oacc[3], a0.w, w);
        fma4(oacc[4], a1.x, w); fma4(oacc[5], a1.y, w);
        fma4(oacc[6], a1.z, w); fma4(oacc[7], a1.w, w);
    }

    float* sp = slab + (size_t)vs * (BB * QQ * HH);
#pragma unroll
    for (int j = 0; j < 8; j++) {
        const int q = qh * 8 + j;
        *(float4*)&sp[((size_t)(b * QQ + qbase + q)) * HH + h0] = oacc[j];
    }
}

// ---------------------------------------------------------------------------
// out = (sum of 16 slabs) * rcp(denom[row]). 131072 float4s, grid 512.
// ---------------------------------------------------------------------------
__global__ __launch_bounds__(256) void reduce_kernel(const float* __restrict__ slab,
                                                     const float* __restrict__ denom,
                                                     float* __restrict__ out) {
    const int i = blockIdx.x * 256 + threadIdx.x;    // float4 index
    const float r = __builtin_amdgcn_rcpf(denom[i >> 7]);
    const float4* s4 = (const float4*)slab;
    float4 s = s4[i];
#pragma unroll
    for (int k = 1; k < 16; k++) {
        const float4 p = s4[(size_t)k * (BB * QQ * HH / 4) + i];
        s.x += p.x; s.y += p.y; s.z += p.z; s.w += p.w;
    }
    s.x *= r; s.y *= r; s.z *= r; s.w *= r;
    ((float4*)out)[i] = s;
}

// ---------------------------------------------------------------------------
extern "C" void kernel_launch(void* const* d_in, const int* in_sizes, int n_in,
                              void* d_out, int out_size, void* d_ws, size_t ws_size,
                              hipStream_t stream) {
    const float* queries = (const float*)d_in[0];  // [B,Q,H]
    const float* values  = (const float*)d_in[1];  // [B,V,H]
    const float* w1      = (const float*)d_in[2];  // [H,U]
    const float* w2      = (const float*)d_in[3];  // [H,U]
    const float* vvec    = (const float*)d_in[4];  // [U]
    float* out = (float*)d_out;

    // ws (floats): pqI[131072] | pvI[1048576] | denom[1024] | slab[16*524288]
    // total ~38.3 MB (reference materializes a 1 GB intermediate; ws is ample)
    float* ws    = (float*)d_ws;
    float* pqI   = ws;
    float* pvI   = pqI + BB * UU * QQ;
    float* denom = pvI + (size_t)BB * UU * VV;
    float* slab  = denom + BB * QQ;

    proj_kernel<<<256 + 32, 256, 0, stream>>>(queries, values, w1, w2, pqI, pvI, denom);
    fused_kernel<<<BB * (QQ / 16) * (VV / 128), 256, 0, stream>>>(pqI, pvI, vvec, values, slab, denom);
    reduce_kernel<<<(BB * QQ * HH) / 4 / 256, 256, 0, stream>>>(slab, denom, out);
}